// Round 4
// baseline (272.089 us; speedup 1.0000x reference)
//
#include <hip/hip_runtime.h>
#include <hip/hip_cooperative_groups.h>
#include <stdint.h>

namespace cg = cooperative_groups;

// Problem constants: N=16384, M=1024, D=1024, fp32 in/out
#define NN 16384
#define MM 1024
#define DD 1024

typedef __attribute__((ext_vector_type(4)))  int   int4v;
typedef __attribute__((ext_vector_type(8)))  int   int8v;   // 32 fp8 (MX MFMA A/B frag)
typedef __attribute__((ext_vector_type(4)))  float f4;
typedef __attribute__((ext_vector_type(16))) float f16v;    // 32x32 MFMA C/D frag

// pack 4 fp32 -> 4 OCP e4m3 bytes in a dword (HW RNE)
__device__ __forceinline__ uint32_t pk4fp8(float a, float b, float c, float d) {
    uint32_t lo = __builtin_amdgcn_cvt_pk_fp8_f32(a, b, 0, false);
    return __builtin_amdgcn_cvt_pk_fp8_f32(c, d, lo, true);
}

// global -> LDS direct copy, 16B per lane (dest = wave-uniform base + lane*16)
#define GLD16(gsrc, ldst)                                                      \
    __builtin_amdgcn_global_load_lds(                                         \
        (const __attribute__((address_space(1))) void*)(gsrc),                \
        (__attribute__((address_space(3))) void*)(ldst), 16, 0, 0)

#define MFMA8(a_, b_, c_)                                                      \
    __builtin_amdgcn_mfma_scale_f32_32x32x64_f8f6f4(                           \
        (a_), (b_), (c_), 0, 0, 0, 0x7F7F7F7F, 0, 0x7F7F7F7F)

// ---- fused prologue (ONE dispatch, UNCHANGED from round 2): blocks
// [0,4352) do row squared-norms + fp32->fp8 convert of x and centers;
// blocks [4352,5376) transpose+convert norm [k][c] -> [c][k] fp8.
// All fp8 outputs stored PRE-SWIZZLED (16B chunk index ^= row&7 per 128B
// group) so the GEMM stages with linear global_load_lds, conflict-free. ----
#define ROW_BLOCKS ((NN + MM) / 4)   // 4352

__global__ __launch_bounds__(256)
void prologue_kernel(const float* __restrict__ x, const float* __restrict__ cen,
                     const float* __restrict__ norm,
                     float* __restrict__ xsq, float* __restrict__ csq,
                     uint32_t* __restrict__ x8, uint32_t* __restrict__ c8,
                     uint8_t* __restrict__ n8) {
    if (blockIdx.x < ROW_BLOCKS) {
        int row  = (blockIdx.x * 256 + threadIdx.x) >> 6;
        int lane = threadIdx.x & 63;
        const float* src; float* sq; uint32_t* ob;
        if (row < NN) { src = x + (size_t)row * DD;  sq = xsq + row;
                        ob = x8 + (size_t)row * (DD / 4); }
        else          { int r = row - NN;
                        src = cen + (size_t)r * DD;  sq = csq + r;
                        ob = c8 + (size_t)r * (DD / 4); }
        const int swz = (row & 7) << 2;     // NN%8==0 so (row-NN)&7 == row&7
        const f4* p = (const f4*)src;
        float s = 0.f;
        for (int i = lane; i < DD / 4; i += 64) {
            f4 v = p[i];
            s = fmaf(v.x, v.x, s); s = fmaf(v.y, v.y, s);
            s = fmaf(v.z, v.z, s); s = fmaf(v.w, v.w, s);
            ob[i ^ swz] = pk4fp8(v.x, v.y, v.z, v.w);   // pre-swizzled store
        }
#pragma unroll
        for (int off = 32; off > 0; off >>= 1) s += __shfl_down(s, off);
        if (lane == 0) *sq = s;
    } else {
        // norm transpose tile: 32x32
        __shared__ float t[32][33];
        int bid2 = blockIdx.x - ROW_BLOCKS;      // 0..1023
        int bx = bid2 & 31, by = bid2 >> 5;
        int tx = threadIdx.x & 31, ty = threadIdx.x >> 5;  // 32 x 8
#pragma unroll
        for (int i = 0; i < 32; i += 8)
            t[ty + i][tx] = norm[(size_t)(by * 32 + ty + i) * MM + bx * 32 + tx];
        __syncthreads();
        int c  = threadIdx.x >> 3;        // 0..31 (local col)
        int rg = (threadIdx.x & 7) * 4;   // 0,4,...,28 (local k group)
        uint32_t u = pk4fp8(t[rg + 0][c], t[rg + 1][c], t[rg + 2][c], t[rg + 3][c]);
        // pre-swizzled store: dword index within row d = by*8 + (tid&7)
        uint32_t* orow = (uint32_t*)&n8[(size_t)(bx * 32 + c) * MM];
        orow[(by * 8 + (threadIdx.x & 7)) ^ ((c & 7) << 2)] = u;
    }
}

// ---- MX-fp8 MFMA GEMM body (round-2 verified 8-phase 256x256 structure,
// transplanted unchanged into a cooperative fused kernel).
// 8 waves (2M x 4N), wave tile 128x64 (4x2 accs), BK=128, dbuf 2x64KB LDS,
// per-phase {ds_read | stage issue} -> barrier -> lgkmcnt(0) -> setprio(1)
// -> 2 MFMA -> setprio(0) -> barrier; staging front-loaded phases 0-3.
constexpr int BM = 256, BN = 256, BK = 128;

__device__ __forceinline__ int8v rdfrag(const uint8_t* base, int row, int cb) {
    const uint8_t* p = base + row * BK;
    int4v lo = *(const int4v*)(p + ((cb ^ (row & 7)) * 16));
    int4v hi = *(const int4v*)(p + (((cb + 1) ^ (row & 7)) * 16));
    return __builtin_shufflevector(lo, hi, 0, 1, 2, 3, 4, 5, 6, 7);
}

template<bool EXP_EPI>
__device__ __forceinline__
void gemm_body(const uint8_t* __restrict__ A, const uint8_t* __restrict__ Bt,
               void* __restrict__ Cv, const float* __restrict__ xsq,
               const float* __restrict__ csq, float gam,
               uint8_t* sAp, uint8_t* sBp)
{
    constexpr int K = 1024, NC = 1024, NIT = K / BK;   // 8 K-tiles

    const int tid  = threadIdx.x;
    const int lane = tid & 63;
    const int wave = tid >> 6;        // 0..7
    const int l31  = lane & 31;
    const int kh   = lane >> 5;
    const int wm   = (wave >> 2) * 128;   // 2 wave-rows
    const int wn   = (wave & 3) * 64;     // 4 wave-cols

    // bijective XCD swizzle: 256 blocks = 8 XCDs x 32 slots
    const int bid  = blockIdx.x;           // 0..255
    const int xcd  = bid & 7;
    const int slot = bid >> 3;             // 0..31
    const int brow = (xcd * 8 + (slot >> 2)) * 256;
    const int bcol = (slot & 3) * 256;

    f16v acc[4][2];
#pragma unroll
    for (int mi = 0; mi < 4; ++mi)
#pragma unroll
        for (int ni = 0; ni < 2; ++ni)
#pragma unroll
            for (int r = 0; r < 16; ++r) acc[mi][ni][r] = 0.f;

    // staging: per issue, 512 threads x 16B = 8KB = 64 rows of 128B
    const int sr = wave * 8 + (lane >> 3);       // 0..63
    const int sc = lane & 7;
    const uint8_t* ga = A  + (size_t)(brow + sr) * K + sc * 16;
    const uint8_t* gb = Bt + (size_t)(bcol + sr) * K + sc * 16;

#define SBUF(b_) (sAp + (b_) * (BM * BK))
#define TBUF(b_) (sBp + (b_) * (BN * BK))

    // prologue: stage tile 0 (8 issues), full drain once
    {
        uint8_t* dA = SBUF(0) + wave * 1024;
        uint8_t* dB = TBUF(0) + wave * 1024;
#pragma unroll
        for (int j = 0; j < 4; ++j) {
            GLD16(ga + (size_t)j * 64 * K, dA + j * 8192);
            GLD16(gb + (size_t)j * 64 * K, dB + j * 8192);
        }
    }
    asm volatile("s_waitcnt vmcnt(0)" ::: "memory");
    __builtin_amdgcn_s_barrier();

#pragma unroll
    for (int it = 0; it < NIT; ++it) {
        const int cur = it & 1;
        const uint8_t* tA = SBUF(cur);
        const uint8_t* tB = TBUF(cur);
        uint8_t* dA = SBUF(cur ^ 1) + wave * 1024;
        uint8_t* dB = TBUF(cur ^ 1) + wave * 1024;
        const size_t koff = (size_t)(it + 1) * BK;
        const bool st = (it + 1 < NIT);

        int8v b0, b1, am;

#define PHASE(mi_, s_, STG)                                                    \
        do {                                                                   \
            STG;                                                               \
            if ((mi_) == 0) {                                                  \
                b0 = rdfrag(tB, wn + l31,      (s_) * 4 + kh * 2);             \
                b1 = rdfrag(tB, wn + 32 + l31, (s_) * 4 + kh * 2);             \
            }                                                                  \
            am = rdfrag(tA, wm + (mi_) * 32 + l31, (s_) * 4 + kh * 2);         \
            __builtin_amdgcn_s_barrier();                                      \
            asm volatile("s_waitcnt lgkmcnt(0)" ::: "memory");                 \
            __builtin_amdgcn_s_setprio(1);                                     \
            acc[mi_][0] = MFMA8(am, b0, acc[mi_][0]);                          \
            acc[mi_][1] = MFMA8(am, b1, acc[mi_][1]);                          \
            __builtin_amdgcn_s_setprio(0);                                     \
            __builtin_amdgcn_s_barrier();                                      \
        } while (0)

        PHASE(0, 0, if (st) { GLD16(ga + koff,                    dA);
                              GLD16(ga + koff + (size_t) 64 * K,  dA +  8192); });
        PHASE(1, 0, if (st) { GLD16(ga + koff + (size_t)128 * K,  dA + 16384);
                              GLD16(ga + koff + (size_t)192 * K,  dA + 24576); });
        PHASE(2, 0, if (st) { GLD16(gb + koff,                    dB);
                              GLD16(gb + koff + (size_t) 64 * K,  dB +  8192); });
        PHASE(3, 0, if (st) { GLD16(gb + koff + (size_t)128 * K,  dB + 16384);
                              GLD16(gb + koff + (size_t)192 * K,  dB + 24576); });
        PHASE(0, 1, );
        PHASE(1, 1, );
        PHASE(2, 1, );
        PHASE(3, 1, );
#undef PHASE

        asm volatile("s_waitcnt vmcnt(0)" ::: "memory");
        __builtin_amdgcn_s_barrier();
    }
#undef SBUF
#undef TBUF

    // C/D layout (32x32, m74/m101): col = lane&31, row = (reg&3)+8*(reg>>2)+4*kh
    if constexpr (EXP_EPI) {
        uint8_t* C = (uint8_t*)Cv;
        float cs[2];
        cs[0] = csq[bcol + wn + l31];
        cs[1] = csq[bcol + wn + 32 + l31];
#pragma unroll
        for (int mi = 0; mi < 4; ++mi)
#pragma unroll
            for (int r = 0; r < 16; ++r) {
                int rl  = (r & 3) + 8 * (r >> 2) + 4 * kh;
                int row = brow + wm + mi * 32 + rl;
                float xs = xsq[row];
                int rsw = (row & 7) << 4;   // pre-swizzle for stage-2 staging
#pragma unroll
                for (int ni = 0; ni < 2; ++ni) {
                    int col = bcol + wn + ni * 32 + l31;
                    float sq = xs + cs[ni] - 2.0f * acc[mi][ni][r];
                    float d = __expf(-gam * sq);   // underflows to 0 (sq ~>1500)
                    C[(size_t)row * NC + (col ^ rsw)] =
                        (uint8_t)(__builtin_amdgcn_cvt_pk_fp8_f32(d, d, 0, false) & 0xFF);
                }
            }
    } else {
        float* C = (float*)Cv;
#pragma unroll
        for (int mi = 0; mi < 4; ++mi)
#pragma unroll
            for (int r = 0; r < 16; ++r) {
                int rl  = (r & 3) + 8 * (r >> 2) + 4 * kh;
                int row = brow + wm + mi * 32 + rl;
#pragma unroll
                for (int ni = 0; ni < 2; ++ni)
                    C[(size_t)row * NC + bcol + wn + ni * 32 + l31] = acc[mi][ni][r];
            }
    }
}

// ---- ROUND 15: fused cooperative GEMM1+GEMM2 (one dispatch, 256 blocks x
// 512 threads = 1 block/CU, co-resident). grid.sync() + device fence between
// phases replaces a kernel launch boundary; also makes the GEMMs visible in
// the rocprof top-k (previously crowded out by 40us poison fills).
__global__ __launch_bounds__(512, 2)
void fused_gemm(const uint8_t* __restrict__ x8, const uint8_t* __restrict__ c8,
                uint8_t* __restrict__ dens8, const uint8_t* __restrict__ n8,
                float* __restrict__ out, const float* __restrict__ xsq,
                const float* __restrict__ csq, const float* __restrict__ gamma_p)
{
    __shared__ __align__(16) uint8_t sA[2][BM * BK];   // 2 x 32 KB
    __shared__ __align__(16) uint8_t sB[2][BN * BK];   // 2 x 32 KB

    // phase B: dens = exp(-g * (xsq + csq - 2 * x @ centers^T)), fp8 out
    gemm_body<true>(x8, c8, dens8, xsq, csq, gamma_p[0], &sA[0][0], &sB[0][0]);

    __threadfence();                 // dens8 visible device-wide (cross-XCD)
    cg::this_grid().sync();

    // phase C: out = dens @ norm (via norm^T), fp32 out
    gemm_body<false>(dens8, n8, out, nullptr, nullptr, 0.f, &sA[0][0], &sB[0][0]);
}

extern "C" void kernel_launch(void* const* d_in, const int* in_sizes, int n_in,
                              void* d_out, int out_size, void* d_ws, size_t ws_size,
                              hipStream_t stream) {
    const float* inputs  = (const float*)d_in[0];   // [N, D]
    const float* centers = (const float*)d_in[1];   // [M, D]
    const float* gamma   = (const float*)d_in[2];   // [1]
    const float* norm    = (const float*)d_in[3];   // [M, M]
    float* out = (float*)d_out;                     // [N, M]

    // ws layout: xsq 64K | csq 4K | c8 1M | n8 1M | dens8 16M  (~18.1 MiB)
    char* w = (char*)d_ws;
    float*   xsq   = (float*)w;
    float*   csq   = (float*)(w + 65536);
    uint8_t* c8    = (uint8_t*)(w + 69632);
    uint8_t* n8    = (uint8_t*)(w + 69632 + (1u << 20));
    uint8_t* dens8 = (uint8_t*)(w + 69632 + (2u << 20));
    // x8 (16 MB) parked in d_out: dead before phase C writes d_out.
    uint32_t* x8   = (uint32_t*)d_out;

    // single fused prologue dispatch (rowsq+cvt for x & centers, norm transpose)
    prologue_kernel<<<ROW_BLOCKS + 1024, 256, 0, stream>>>(
        inputs, centers, norm, xsq, csq, x8, (uint32_t*)c8, n8);

    // fused cooperative GEMM1 + grid.sync + GEMM2
    const uint8_t* x8b = (const uint8_t*)x8;
    void* kargs[] = { (void*)&x8b, (void*)&c8, (void*)&dens8, (void*)&n8,
                      (void*)&out, (void*)&xsq, (void*)&csq, (void*)&gamma };
    hipLaunchCooperativeKernel((const void*)fused_gemm, dim3(256), dim3(512),
                               kargs, 0, stream);
}

// Round 5
// 197.924 us; speedup vs baseline: 1.3747x; 1.3747x over previous
//
#include <hip/hip_runtime.h>
#include <stdint.h>

// Problem constants: N=16384, M=1024, D=1024, fp32 in/out
#define NN 16384
#define MM 1024
#define DD 1024

typedef __attribute__((ext_vector_type(4)))  int   int4v;
typedef __attribute__((ext_vector_type(8)))  int   int8v;   // 32 fp8 (MX MFMA A/B frag)
typedef __attribute__((ext_vector_type(4)))  float f4;
typedef __attribute__((ext_vector_type(16))) float f16v;    // 32x32 MFMA C/D frag

// pack 4 fp32 -> 4 OCP e4m3 bytes in a dword (HW RNE)
__device__ __forceinline__ uint32_t pk4fp8(float a, float b, float c, float d) {
    uint32_t lo = __builtin_amdgcn_cvt_pk_fp8_f32(a, b, 0, false);
    return __builtin_amdgcn_cvt_pk_fp8_f32(c, d, lo, true);
}

// global -> LDS direct copy, 16B per lane (dest = wave-uniform base + lane*16)
#define GLD16(gsrc, ldst)                                                      \
    __builtin_amdgcn_global_load_lds(                                         \
        (const __attribute__((address_space(1))) void*)(gsrc),                \
        (__attribute__((address_space(3))) void*)(ldst), 16, 0, 0)

#define MFMA8(a_, b_, c_)                                                      \
    __builtin_amdgcn_mfma_scale_f32_32x32x64_f8f6f4(                           \
        (a_), (b_), (c_), 0, 0, 0, 0x7F7F7F7F, 0, 0x7F7F7F7F)

// ---- fused prologue (ONE dispatch): blocks [0,4352) do row squared-norms +
// fp32->fp8 convert of x and centers; blocks [4352,5376) transpose+convert
// norm [k][c] -> [c][k] fp8.
// ROUND 16: only the GEMM *A* operands (x8; dens8 via GEMM1 epilogue) are
// stored PRE-SWIZZLED (16B chunk ^= row&7 per 128B group) for the linear
// global_load_lds staging path. B operands (c8, n8) are stored PLAIN: the
// GEMM now reads B fragments directly from global (L2-resident, 1 MB each),
// bypassing LDS entirely for B. ----
#define ROW_BLOCKS ((NN + MM) / 4)   // 4352

__global__ __launch_bounds__(256)
void prologue_kernel(const float* __restrict__ x, const float* __restrict__ cen,
                     const float* __restrict__ norm,
                     float* __restrict__ xsq, float* __restrict__ csq,
                     uint32_t* __restrict__ x8, uint32_t* __restrict__ c8,
                     uint8_t* __restrict__ n8) {
    if (blockIdx.x < ROW_BLOCKS) {
        int row  = (blockIdx.x * 256 + threadIdx.x) >> 6;
        int lane = threadIdx.x & 63;
        const float* src; float* sq; uint32_t* ob;
        if (row < NN) { src = x + (size_t)row * DD;  sq = xsq + row;
                        ob = x8 + (size_t)row * (DD / 4); }
        else          { int r = row - NN;
                        src = cen + (size_t)r * DD;  sq = csq + r;
                        ob = c8 + (size_t)r * (DD / 4); }
        // x8 (GEMM1 A): pre-swizzled. c8 (GEMM1 B): plain.
        const int swz = (row < NN) ? ((row & 7) << 2) : 0;
        const f4* p = (const f4*)src;
        float s = 0.f;
        for (int i = lane; i < DD / 4; i += 64) {
            f4 v = p[i];
            s = fmaf(v.x, v.x, s); s = fmaf(v.y, v.y, s);
            s = fmaf(v.z, v.z, s); s = fmaf(v.w, v.w, s);
            ob[i ^ swz] = pk4fp8(v.x, v.y, v.z, v.w);
        }
#pragma unroll
        for (int off = 32; off > 0; off >>= 1) s += __shfl_down(s, off);
        if (lane == 0) *sq = s;
    } else {
        // norm transpose tile: 32x32 -> n8 (GEMM2 B): plain [c][k] fp8
        __shared__ float t[32][33];
        int bid2 = blockIdx.x - ROW_BLOCKS;      // 0..1023
        int bx = bid2 & 31, by = bid2 >> 5;
        int tx = threadIdx.x & 31, ty = threadIdx.x >> 5;  // 32 x 8
#pragma unroll
        for (int i = 0; i < 32; i += 8)
            t[ty + i][tx] = norm[(size_t)(by * 32 + ty + i) * MM + bx * 32 + tx];
        __syncthreads();
        int c  = threadIdx.x >> 3;        // 0..31 (local col)
        int rg = (threadIdx.x & 7) * 4;   // 0,4,...,28 (local k group)
        uint32_t u = pk4fp8(t[rg + 0][c], t[rg + 1][c], t[rg + 2][c], t[rg + 3][c]);
        uint32_t* orow = (uint32_t*)&n8[(size_t)(bx * 32 + c) * MM];
        orow[by * 8 + (threadIdx.x & 7)] = u;
    }
}

// ---- MX-fp8 MFMA GEMM, ROUND 16: round-0 structure (128x128 tile, 4 waves,
// 64x64/wave, BK=128, 2-phase gload_lds staging — best measured) with the B
// operand moved OUT of LDS: B fragments are loaded directly global->reg
// (2 x dwordx4 per frag, prefetched one K-tile ahead; B is 1 MB, L2-resident).
// LDS traffic per block-K-tile drops 96 KB -> 48 KB (theory: LDS-BW-bound),
// LDS size 32 KB -> 16 KB, gload_lds issues 8 -> 4.
// A: [row][k] fp8 PRE-SWIZZLED (chunk ^= row&7 per 128B); B: [col][k] plain.
// EXP_EPI: C(fp8, pre-swizzled)=exp(-g*(xsq+csq-2acc)); else C(fp32)=acc.
constexpr int BM = 128, BN = 128, BK = 128;

__device__ __forceinline__ int8v rdfrag(const uint8_t* base, int row, int cb) {
    const uint8_t* p = base + row * BK;
    int4v lo = *(const int4v*)(p + ((cb ^ (row & 7)) * 16));
    int4v hi = *(const int4v*)(p + (((cb + 1) ^ (row & 7)) * 16));
    return __builtin_shufflevector(lo, hi, 0, 1, 2, 3, 4, 5, 6, 7);
}

template<bool EXP_EPI>
__global__ __launch_bounds__(256)
void mfma_gemm_fp8(const uint8_t* __restrict__ A, const uint8_t* __restrict__ B,
                   void* __restrict__ Cv, const float* __restrict__ xsq,
                   const float* __restrict__ csq, const float* __restrict__ gamma_p)
{
    constexpr int K = 1024, NC = 1024, NIT = K / BK;
    __shared__ __align__(16) uint8_t sA[BM * BK];   // 16 KB, A only

    const int tid  = threadIdx.x;
    const int lane = tid & 63;
    const int wave = tid >> 6;        // 0..3
    const int l31  = lane & 31;
    const int kh   = lane >> 5;
    const int wm   = (wave >> 1) * 64;
    const int wn   = (wave & 1) * 64;

    // XCD swizzle (verified: FETCH 264->33 MB)
    const int bid  = blockIdx.x;           // 0..1023
    const int xcd  = bid & 7;
    const int slot = bid >> 3;
    const int bcol = (slot & 7) * 128;
    const int brow = ((xcd << 4) | (slot >> 3)) * 128;

    const int r8  = lane >> 3;             // staging row-in-group 0..7
    const int c8i = lane & 7;              // staging 16B chunk 0..7

    const float gam = EXP_EPI ? gamma_p[0] : 0.f;

    f16v acc[2][2];
#pragma unroll
    for (int mi = 0; mi < 2; ++mi)
#pragma unroll
        for (int ni = 0; ni < 2; ++ni)
#pragma unroll
            for (int r = 0; r < 16; ++r) acc[mi][ni][r] = 0.f;

    // A staging (pre-swizzled global -> linear LDS copy)
    const uint8_t* ga = A + (size_t)(brow + wave * 32 + r8) * K + c8i * 16;
    uint8_t* la = &sA[(wave * 32) * BK];   // wave-uniform base; HW adds lane*16

    // B direct-from-global: per-lane column pointers (plain [col][k] layout).
    // Frag (it, s, ni) = B[col][it*128 + s*64 + kh*32 .. +32) = 2 x 16B loads.
    const uint8_t* gb0 = B + (size_t)(bcol + wn + l31) * K + kh * 32;
    const uint8_t* gb1 = B + (size_t)(bcol + wn + 32 + l31) * K + kh * 32;

    int8v bf[2][2][2];   // [K-tile parity][s][ni] — all indices unroll-constant

#define LDB(P_, IT_)                                                           \
    do {                                                                       \
        _Pragma("unroll")                                                      \
        for (int s_ = 0; s_ < 2; ++s_) {                                       \
            const uint8_t* p0_ = gb0 + (IT_) * BK + s_ * 64;                   \
            const uint8_t* p1_ = gb1 + (IT_) * BK + s_ * 64;                   \
            int4v lo0_ = *(const int4v*)p0_;                                   \
            int4v hi0_ = *(const int4v*)(p0_ + 16);                            \
            int4v lo1_ = *(const int4v*)p1_;                                   \
            int4v hi1_ = *(const int4v*)(p1_ + 16);                            \
            bf[P_][s_][0] = __builtin_shufflevector(lo0_, hi0_, 0,1,2,3,4,5,6,7);\
            bf[P_][s_][1] = __builtin_shufflevector(lo1_, hi1_, 0,1,2,3,4,5,6,7);\
        }                                                                      \
    } while (0)

    // prologue: stage A tile 0 + load B tile 0; single drain
#pragma unroll
    for (int i = 0; i < 4; ++i) GLD16(ga + (size_t)i * 8 * K, la + i * 8 * BK);
    LDB(0, 0);
    __syncthreads();                      // compiler drains vmcnt -> tile 0 ready

#pragma unroll
    for (int it = 0; it < NIT; ++it) {
        const int cur = it & 1;           // unrolled -> compile-time constant
#pragma unroll
        for (int s = 0; s < 2; ++s) {     // two 64-deep k-steps per tile
            const int cb = s * 4 + kh * 2;
            int8v a0 = rdfrag(sA, wm + l31,      cb);
            int8v a1 = rdfrag(sA, wm + 32 + l31, cb);
            acc[0][0] = MFMA8(a0, bf[cur][s][0], acc[0][0]);
            acc[0][1] = MFMA8(a0, bf[cur][s][1], acc[0][1]);
            acc[1][0] = MFMA8(a1, bf[cur][s][0], acc[1][0]);
            acc[1][1] = MFMA8(a1, bf[cur][s][1], acc[1][1]);
        }
        if (it + 1 < NIT) {
            __syncthreads();              // all waves done reading sA
            const size_t koff = (size_t)(it + 1) * BK;
#pragma unroll
            for (int i = 0; i < 4; ++i)
                GLD16(ga + koff + (size_t)i * 8 * K, la + i * 8 * BK);
            LDB(cur ^ 1, it + 1);         // B latency overlaps the A-stage drain
            __syncthreads();              // drain -> tile it+1 + B regs ready
        }
    }
#undef LDB

    // C/D layout (32x32, m74/m101): col = lane&31, row = (reg&3)+8*(reg>>2)+4*kh
    if constexpr (EXP_EPI) {
        uint8_t* C = (uint8_t*)Cv;
        float cs[2];
        cs[0] = csq[bcol + wn + l31];
        cs[1] = csq[bcol + wn + 32 + l31];
#pragma unroll
        for (int mi = 0; mi < 2; ++mi)
#pragma unroll
            for (int r = 0; r < 16; ++r) {
                int rl  = (r & 3) + 8 * (r >> 2) + 4 * kh;
                int row = brow + wm + mi * 32 + rl;
                float xs = xsq[row];
                int rsw = (row & 7) << 4;   // pre-swizzle for stage-2 A staging
#pragma unroll
                for (int ni = 0; ni < 2; ++ni) {
                    int col = bcol + wn + ni * 32 + l31;
                    float sq = xs + cs[ni] - 2.0f * acc[mi][ni][r];
                    float d = __expf(-gam * sq);   // underflows to 0 (sq ~>1500)
                    C[(size_t)row * NC + (col ^ rsw)] =
                        (uint8_t)(__builtin_amdgcn_cvt_pk_fp8_f32(d, d, 0, false) & 0xFF);
                }
            }
    } else {
        float* C = (float*)Cv;
#pragma unroll
        for (int mi = 0; mi < 2; ++mi)
#pragma unroll
            for (int r = 0; r < 16; ++r) {
                int rl  = (r & 3) + 8 * (r >> 2) + 4 * kh;
                int row = brow + wm + mi * 32 + rl;
#pragma unroll
                for (int ni = 0; ni < 2; ++ni)
                    C[(size_t)row * NC + bcol + wn + ni * 32 + l31] = acc[mi][ni][r];
            }
    }
}

extern "C" void kernel_launch(void* const* d_in, const int* in_sizes, int n_in,
                              void* d_out, int out_size, void* d_ws, size_t ws_size,
                              hipStream_t stream) {
    const float* inputs  = (const float*)d_in[0];   // [N, D]
    const float* centers = (const float*)d_in[1];   // [M, D]
    const float* gamma   = (const float*)d_in[2];   // [1]
    const float* norm    = (const float*)d_in[3];   // [M, M]
    float* out = (float*)d_out;                     // [N, M]

    // ws layout: xsq 64K | csq 4K | c8 1M | n8 1M | dens8 16M  (~18.1 MiB)
    char* w = (char*)d_ws;
    float*   xsq   = (float*)w;
    float*   csq   = (float*)(w + 65536);
    uint8_t* c8    = (uint8_t*)(w + 69632);
    uint8_t* n8    = (uint8_t*)(w + 69632 + (1u << 20));
    uint8_t* dens8 = (uint8_t*)(w + 69632 + (2u << 20));
    // x8 (16 MB) parked in d_out: dead before stage 2 writes d_out.
    uint32_t* x8   = (uint32_t*)d_out;

    // single fused prologue dispatch (rowsq+cvt for x & centers, norm transpose)
    prologue_kernel<<<ROW_BLOCKS + 1024, 256, 0, stream>>>(
        inputs, centers, norm, xsq, csq, x8, (uint32_t*)c8, n8);

    // stage 1: dens = exp(-g * (xsq + csq - 2 * x @ centers^T)), fp8 out
    mfma_gemm_fp8<true><<<1024, 256, 0, stream>>>(
        (const uint8_t*)x8, c8, dens8, xsq, csq, gamma);
    // stage 2: out = dens @ norm (via norm^T), fp32 out
    mfma_gemm_fp8<false><<<1024, 256, 0, stream>>>(
        dens8, n8, out, nullptr, nullptr, nullptr);
}

// Round 6
// 160.806 us; speedup vs baseline: 1.6920x; 1.2308x over previous
//
#include <hip/hip_runtime.h>
#include <stdint.h>

// Problem constants: N=16384, M=1024, D=1024, fp32 in/out
#define NN 16384
#define MM 1024
#define DD 1024

typedef __attribute__((ext_vector_type(4)))  int   int4v;
typedef __attribute__((ext_vector_type(8)))  int   int8v;   // 32 fp8 (MX MFMA A/B frag)
typedef __attribute__((ext_vector_type(4)))  float f4;
typedef __attribute__((ext_vector_type(16))) float f16v;    // 32x32 MFMA C/D frag

// pack 4 fp32 -> 4 OCP e4m3 bytes in a dword (HW RNE)
__device__ __forceinline__ uint32_t pk4fp8(float a, float b, float c, float d) {
    uint32_t lo = __builtin_amdgcn_cvt_pk_fp8_f32(a, b, 0, false);
    return __builtin_amdgcn_cvt_pk_fp8_f32(c, d, lo, true);
}

// global -> LDS direct copy, 16B per lane (dest = wave-uniform base + lane*16)
#define GLD16(gsrc, ldst)                                                      \
    __builtin_amdgcn_global_load_lds(                                         \
        (const __attribute__((address_space(1))) void*)(gsrc),                \
        (__attribute__((address_space(3))) void*)(ldst), 16, 0, 0)

#define MFMA8(a_, b_, c_)                                                      \
    __builtin_amdgcn_mfma_scale_f32_32x32x64_f8f6f4(                           \
        (a_), (b_), (c_), 0, 0, 0, 0x7F7F7F7F, 0, 0x7F7F7F7F)

// ---- fused prologue (ONE dispatch, round-0 version, all operands
// PRE-SWIZZLED): blocks [0,4352) do row squared-norms + fp32->fp8 convert of
// x and centers; blocks [4352,5376) transpose+convert norm [k][c]->[c][k] fp8.
// Pre-swizzle: 16B chunk index ^= row&7 within each 128B group (dword index
// ^= (row&7)<<2), so the GEMM stages with linear global_load_lds and reads
// with the XOR-swizzled addressing, conflict-free. ----
#define ROW_BLOCKS ((NN + MM) / 4)   // 4352

__global__ __launch_bounds__(256)
void prologue_kernel(const float* __restrict__ x, const float* __restrict__ cen,
                     const float* __restrict__ norm,
                     float* __restrict__ xsq, float* __restrict__ csq,
                     uint32_t* __restrict__ x8, uint32_t* __restrict__ c8,
                     uint8_t* __restrict__ n8) {
    if (blockIdx.x < ROW_BLOCKS) {
        int row  = (blockIdx.x * 256 + threadIdx.x) >> 6;
        int lane = threadIdx.x & 63;
        const float* src; float* sq; uint32_t* ob;
        if (row < NN) { src = x + (size_t)row * DD;  sq = xsq + row;
                        ob = x8 + (size_t)row * (DD / 4); }
        else          { int r = row - NN;
                        src = cen + (size_t)r * DD;  sq = csq + r;
                        ob = c8 + (size_t)r * (DD / 4); }
        const int swz = (row & 7) << 2;     // NN%8==0 so (row-NN)&7 == row&7
        const f4* p = (const f4*)src;
        float s = 0.f;
        for (int i = lane; i < DD / 4; i += 64) {
            f4 v = p[i];
            s = fmaf(v.x, v.x, s); s = fmaf(v.y, v.y, s);
            s = fmaf(v.z, v.z, s); s = fmaf(v.w, v.w, s);
            ob[i ^ swz] = pk4fp8(v.x, v.y, v.z, v.w);   // pre-swizzled store
        }
#pragma unroll
        for (int off = 32; off > 0; off >>= 1) s += __shfl_down(s, off);
        if (lane == 0) *sq = s;
    } else {
        // norm transpose tile: 32x32 -> n8 [c][k] fp8, pre-swizzled
        __shared__ float t[32][33];
        int bid2 = blockIdx.x - ROW_BLOCKS;      // 0..1023
        int bx = bid2 & 31, by = bid2 >> 5;
        int tx = threadIdx.x & 31, ty = threadIdx.x >> 5;  // 32 x 8
#pragma unroll
        for (int i = 0; i < 32; i += 8)
            t[ty + i][tx] = norm[(size_t)(by * 32 + ty + i) * MM + bx * 32 + tx];
        __syncthreads();
        int c  = threadIdx.x >> 3;        // 0..31 (local col)
        int rg = (threadIdx.x & 7) * 4;   // 0,4,...,28 (local k group)
        uint32_t u = pk4fp8(t[rg + 0][c], t[rg + 1][c], t[rg + 2][c], t[rg + 3][c]);
        // pre-swizzled store: dword index within row d = by*8 + (tid&7)
        uint32_t* orow = (uint32_t*)&n8[(size_t)(bx * 32 + c) * MM];
        orow[(by * 8 + (threadIdx.x & 7)) ^ ((c & 7) << 2)] = u;
    }
}

// ---- MX-fp8 MFMA GEMM, ROUND 17: 256x256 tile, 512 threads, 8 waves
// (2M x 4N), wave tile 128x64 (4x2 accs) -> 1.5 ds_reads/MFMA (vs 2.0 at
// 64x64: fixes the LDS-port:MFMA imbalance diagnosed in rounds 4-5), BK=128,
// 32x32x64 MX MFMA, double-buffered 2x64KB LDS, SIMPLE round-0 schedule:
// per K-tile { issue stage(t+1) -> compute(t) -> vmcnt(0) [aged ~400cy] ->
// s_barrier }. No per-phase barriers (round-2's 16 barriers/K-tile were the
// overhead), no B-from-global (round-4's gather was the failure).
// Both operands PRE-SWIZZLED in global (chunk ^= row&7 per 128B) -> linear
// global_load_lds staging + XOR-swizzled ds_read, conflict-free.
// A: [row][k] fp8; Bt: [col][k] fp8. EXP_EPI: C(fp8, pre-swizzled)=
// exp(-g*(xsq+csq-2acc)); else C(fp32, linear)=acc.
constexpr int BM = 256, BN = 256, BK = 128;

__device__ __forceinline__ int8v rdfrag(const uint8_t* base, int row, int cb) {
    const uint8_t* p = base + row * BK;
    int4v lo = *(const int4v*)(p + ((cb ^ (row & 7)) * 16));
    int4v hi = *(const int4v*)(p + (((cb + 1) ^ (row & 7)) * 16));
    return __builtin_shufflevector(lo, hi, 0, 1, 2, 3, 4, 5, 6, 7);
}

template<bool EXP_EPI>
__global__ __launch_bounds__(512, 2)
void mfma_gemm_fp8(const uint8_t* __restrict__ A, const uint8_t* __restrict__ Bt,
                   void* __restrict__ Cv, const float* __restrict__ xsq,
                   const float* __restrict__ csq, const float* __restrict__ gamma_p)
{
    constexpr int K = 1024, NC = 1024, NIT = K / BK;   // 8 K-tiles
    __shared__ __align__(16) uint8_t sA[2][BM * BK];   // 2 x 32 KB
    __shared__ __align__(16) uint8_t sB[2][BN * BK];   // 2 x 32 KB

    const int tid  = threadIdx.x;
    const int lane = tid & 63;
    const int wave = tid >> 6;        // 0..7
    const int l31  = lane & 31;
    const int kh   = lane >> 5;
    const int wm   = (wave >> 2) * 128;   // 2 wave-rows
    const int wn   = (wave & 3) * 64;     // 4 wave-cols

    // bijective XCD swizzle: 256 blocks = 8 XCDs x 32 slots
    const int bid  = blockIdx.x;           // 0..255
    const int xcd  = bid & 7;
    const int slot = bid >> 3;             // 0..31
    const int brow = (xcd * 8 + (slot >> 2)) * 256;
    const int bcol = (slot & 3) * 256;

    const float gam = EXP_EPI ? gamma_p[0] : 0.f;

    f16v acc[4][2];
#pragma unroll
    for (int mi = 0; mi < 4; ++mi)
#pragma unroll
        for (int ni = 0; ni < 2; ++ni)
#pragma unroll
            for (int r = 0; r < 16; ++r) acc[mi][ni][r] = 0.f;

    // staging: per issue, 512 threads x 16B = 8KB = 64 rows of 128B.
    // thread -> row = j*64 + wave*8 + (lane>>3), chunk = lane&7 (global is
    // pre-swizzled so a linear copy reproduces the swizzled LDS image).
    const int sr = wave * 8 + (lane >> 3);       // 0..63
    const int sc = lane & 7;
    const uint8_t* ga = A  + (size_t)(brow + sr) * K + sc * 16;
    const uint8_t* gb = Bt + (size_t)(bcol + sr) * K + sc * 16;

    // prologue: stage tile 0 (8 issues), drain, barrier
    {
        uint8_t* dA = &sA[0][wave * 1024];
        uint8_t* dB = &sB[0][wave * 1024];
#pragma unroll
        for (int j = 0; j < 4; ++j) {
            GLD16(ga + (size_t)j * 64 * K, dA + j * 8192);
            GLD16(gb + (size_t)j * 64 * K, dB + j * 8192);
        }
    }
    asm volatile("s_waitcnt vmcnt(0)" ::: "memory");
    __builtin_amdgcn_s_barrier();

#pragma unroll
    for (int it = 0; it < NIT; ++it) {
        const int cur = it & 1;           // unrolled -> compile-time constant
        // issue next tile FIRST: its HBM latency hides under compute below
        if (it + 1 < NIT) {
            uint8_t* dA = &sA[cur ^ 1][wave * 1024];
            uint8_t* dB = &sB[cur ^ 1][wave * 1024];
            const size_t koff = (size_t)(it + 1) * BK;
#pragma unroll
            for (int j = 0; j < 4; ++j) {
                GLD16(ga + koff + (size_t)j * 64 * K, dA + j * 8192);
                GLD16(gb + koff + (size_t)j * 64 * K, dB + j * 8192);
            }
        }
        const uint8_t* tA = &sA[cur][0];
        const uint8_t* tB = &sB[cur][0];
#pragma unroll
        for (int s = 0; s < 2; ++s) {     // two 64-deep k-steps per tile
            const int cb = s * 4 + kh * 2;
            int8v b0 = rdfrag(tB, wn + l31,      cb);
            int8v b1 = rdfrag(tB, wn + 32 + l31, cb);
#pragma unroll
            for (int mi = 0; mi < 4; ++mi) {
                int8v am = rdfrag(tA, wm + mi * 32 + l31, cb);
                acc[mi][0] = MFMA8(am, b0, acc[mi][0]);
                acc[mi][1] = MFMA8(am, b1, acc[mi][1]);
            }
        }
        // drain own stage loads (aged by the whole compute phase), then sync:
        // after the barrier, tile it+1 is fully resident for every wave.
        asm volatile("s_waitcnt vmcnt(0)" ::: "memory");
        __builtin_amdgcn_s_barrier();
    }

    // C/D layout (32x32, m74/m101): col = lane&31, row = (reg&3)+8*(reg>>2)+4*kh
    if constexpr (EXP_EPI) {
        uint8_t* C = (uint8_t*)Cv;
        float cs[2];
        cs[0] = csq[bcol + wn + l31];
        cs[1] = csq[bcol + wn + 32 + l31];
#pragma unroll
        for (int mi = 0; mi < 4; ++mi)
#pragma unroll
            for (int r = 0; r < 16; ++r) {
                int rl  = (r & 3) + 8 * (r >> 2) + 4 * kh;
                int row = brow + wm + mi * 32 + rl;
                float xs = xsq[row];
                int rsw = (row & 7) << 4;   // pre-swizzle for stage-2 staging
#pragma unroll
                for (int ni = 0; ni < 2; ++ni) {
                    int col = bcol + wn + ni * 32 + l31;
                    float sq = xs + cs[ni] - 2.0f * acc[mi][ni][r];
                    float d = __expf(-gam * sq);   // underflows to 0 (sq ~>1500)
                    C[(size_t)row * NC + (col ^ rsw)] =
                        (uint8_t)(__builtin_amdgcn_cvt_pk_fp8_f32(d, d, 0, false) & 0xFF);
                }
            }
    } else {
        float* C = (float*)Cv;
#pragma unroll
        for (int mi = 0; mi < 4; ++mi)
#pragma unroll
            for (int r = 0; r < 16; ++r) {
                int rl  = (r & 3) + 8 * (r >> 2) + 4 * kh;
                int row = brow + wm + mi * 32 + rl;
#pragma unroll
                for (int ni = 0; ni < 2; ++ni)
                    C[(size_t)row * NC + bcol + wn + ni * 32 + l31] = acc[mi][ni][r];
            }
    }
}

extern "C" void kernel_launch(void* const* d_in, const int* in_sizes, int n_in,
                              void* d_out, int out_size, void* d_ws, size_t ws_size,
                              hipStream_t stream) {
    const float* inputs  = (const float*)d_in[0];   // [N, D]
    const float* centers = (const float*)d_in[1];   // [M, D]
    const float* gamma   = (const float*)d_in[2];   // [1]
    const float* norm    = (const float*)d_in[3];   // [M, M]
    float* out = (float*)d_out;                     // [N, M]

    // ws layout: xsq 64K | csq 4K | c8 1M | n8 1M | dens8 16M  (~18.1 MiB)
    char* w = (char*)d_ws;
    float*   xsq   = (float*)w;
    float*   csq   = (float*)(w + 65536);
    uint8_t* c8    = (uint8_t*)(w + 69632);
    uint8_t* n8    = (uint8_t*)(w + 69632 + (1u << 20));
    uint8_t* dens8 = (uint8_t*)(w + 69632 + (2u << 20));
    // x8 (16 MB) parked in d_out: dead before stage 2 writes d_out.
    uint32_t* x8   = (uint32_t*)d_out;

    // single fused prologue dispatch (rowsq+cvt for x & centers, norm transpose)
    prologue_kernel<<<ROW_BLOCKS + 1024, 256, 0, stream>>>(
        inputs, centers, norm, xsq, csq, x8, (uint32_t*)c8, n8);

    // stage 1: dens = exp(-g * (xsq + csq - 2 * x @ centers^T)), fp8 out
    mfma_gemm_fp8<true><<<256, 512, 0, stream>>>(
        (const uint8_t*)x8, c8, dens8, xsq, csq, gamma);
    // stage 2: out = dens @ norm (via norm^T), fp32 out
    mfma_gemm_fp8<false><<<256, 512, 0, stream>>>(
        dens8, n8, out, nullptr, nullptr, nullptr);
}